// Round 1
// baseline (804.574 us; speedup 1.0000x reference)
//
#include <hip/hip_runtime.h>

// VectorBasis: fused edge-expansion + scatter + per-atom contraction.
// out[a,m,o] = sum_{edges e with center a} fc(d)*Y[m] * sum_d (R(n) x alch(q))[d] * ce[spec_a][d] * Wc[o][d]
// Per edge: compute t[o] (3 dots over D=32 with per-species M in LDS), then 9 atomicAdds.

constexpr int NSP  = 4;   // species
constexpr int NRAD = 8;   // radial functions
constexpr int NPS  = 4;   // pseudo species
constexpr int DDIM = NRAD * NPS;  // 32

__global__ __launch_bounds__(256) void vb_edge_kernel(
    const float* __restrict__ vecs,       // (E,3)
    const int*   __restrict__ centers,    // (E,)
    const int*   __restrict__ neighbors,  // (E,)
    const int*   __restrict__ species,    // (A,)
    const float* __restrict__ W_alch,     // (NSP, NPS)
    const float* __restrict__ cemb,       // (NSP, D)
    const float* __restrict__ Wc,         // (3, D)
    float*       __restrict__ out,        // (A,3,3)
    int E)
{
    // M[o][d][s] = cemb[s][d] * Wc[o][d]; species index innermost -> 4 adjacent
    // banks, conflict-free for random per-lane species.
    __shared__ float sM[3][DDIM][NSP];    // 384 floats
    __shared__ float sAl[NPS][NSP];       // 16 floats, transposed W_alch

    for (int i = threadIdx.x; i < 3 * DDIM * NSP; i += blockDim.x) {
        int s  = i & 3;
        int dd = (i >> 2) & 31;
        int o  = i >> 7;
        sM[o][dd][s] = cemb[s * DDIM + dd] * Wc[o * DDIM + dd];
    }
    if (threadIdx.x < NPS * NSP) {
        int q = threadIdx.x >> 2;
        int s = threadIdx.x & 3;
        sAl[q][s] = W_alch[s * NPS + q];
    }
    __syncthreads();

    int e = blockIdx.x * blockDim.x + threadIdx.x;
    if (e >= E) return;

    float vx = vecs[3 * e + 0];
    float vy = vecs[3 * e + 1];
    float vz = vecs[3 * e + 2];
    int c  = centers[e];
    int nb = neighbors[e];
    int sn = species[nb];
    int sc = species[c];

    float d2    = vx * vx + vy * vy + vz * vz + 1e-12f;
    float d     = sqrtf(d2);
    float inv_d = 1.0f / d;

    const float PI = 3.14159265358979323846f;
    const float RCUT = 5.0f, INNER = 4.5f, INVW = 2.0f;  // 1/width
    float taper = 0.5f * (cosf(PI * (d - INNER) * INVW) + 1.0f);
    float fc = (d < INNER) ? 1.0f : ((d < RCUT) ? taper : 0.0f);

    // R[n] = sin((n+1)*theta)/d via Chebyshev recurrence (1 sinf + 1 cosf).
    float theta = (PI / RCUT) * d;
    float s1 = sinf(theta);
    float c1 = cosf(theta);
    float two_c = 2.0f * c1;
    float R[NRAD];
    R[0] = s1 * inv_d;
    float sm2 = 0.0f, sm1 = s1;
    #pragma unroll
    for (int n = 1; n < NRAD; n++) {
        float s = two_c * sm1 - sm2;
        sm2 = sm1; sm1 = s;
        R[n] = s * inv_d;
    }

    float a0 = sAl[0][sn], a1 = sAl[1][sn], a2 = sAl[2][sn], a3 = sAl[3][sn];

    float tacc[3];
    #pragma unroll
    for (int o = 0; o < 3; o++) {
        float acc = 0.0f;
        #pragma unroll
        for (int n = 0; n < NRAD; n++) {
            int dbase = n * NPS;
            float w = sM[o][dbase + 0][sc] * a0
                    + sM[o][dbase + 1][sc] * a1
                    + sM[o][dbase + 2][sc] * a2
                    + sM[o][dbase + 3][sc] * a3;
            acc += R[n] * w;
        }
        tacc[o] = acc;
    }

    // Y order (-1,0,1) -> (y,z,x)/d
    float g0 = fc * vy * inv_d;
    float g1 = fc * vz * inv_d;
    float g2 = fc * vx * inv_d;

    float* op = out + (size_t)c * 9;
    atomicAdd(op + 0, g0 * tacc[0]);
    atomicAdd(op + 1, g0 * tacc[1]);
    atomicAdd(op + 2, g0 * tacc[2]);
    atomicAdd(op + 3, g1 * tacc[0]);
    atomicAdd(op + 4, g1 * tacc[1]);
    atomicAdd(op + 5, g1 * tacc[2]);
    atomicAdd(op + 6, g2 * tacc[0]);
    atomicAdd(op + 7, g2 * tacc[1]);
    atomicAdd(op + 8, g2 * tacc[2]);
}

extern "C" void kernel_launch(void* const* d_in, const int* in_sizes, int n_in,
                              void* d_out, int out_size, void* d_ws, size_t ws_size,
                              hipStream_t stream) {
    const float* vecs      = (const float*)d_in[0];
    const int*   centers   = (const int*)d_in[1];
    const int*   neighbors = (const int*)d_in[2];
    const int*   species   = (const int*)d_in[3];
    // d_in[4] structures, d_in[5] atom_index_in_structure: unused by reference
    const float* W_alch    = (const float*)d_in[6];
    const float* cemb      = (const float*)d_in[7];
    const float* Wc        = (const float*)d_in[8];
    float*       out       = (float*)d_out;

    int E = in_sizes[1];

    hipMemsetAsync(d_out, 0, (size_t)out_size * sizeof(float), stream);

    int block = 256;
    int grid  = (E + block - 1) / block;
    vb_edge_kernel<<<grid, block, 0, stream>>>(vecs, centers, neighbors, species,
                                               W_alch, cemb, Wc, out, E);
}